// Round 6
// baseline (4591.747 us; speedup 1.0000x reference)
//
#include <hip/hip_runtime.h>
#include <math.h>

#define NBLK 256
#define NTHR 512
#define Bsz  32
#define Hsz  512
#define Vsz  32000
#define BH   (Bsz*Hsz)
#define LDP  516         // LDS row stride (floats): 512 + 4 pad
#define CBLK 250         // blocks doing logits (128 rows each)
#define EPS  0.0045f     // bf16 dot-product error coefficient (provable bound w/ margin)

// ---- ws layout (bytes) ----
#define WS_HBUF   0            // 2*BH floats
#define WS_PACKED 131072       // 32 x 128B (ull key64 per b)
#define WS_PLB    135168       // (unused, kept for layout stability)
#define WS_BAR    139264       // 17 x 128B tree barrier
#define WS_WPACK  143360       // 250*8*16*1024 bytes (bf16 B-frags)
#define WS_WNORM  32911360     // 32000 floats (EPS * ||w_n||2)
#define WS_NEEDED 33039360

typedef short short8 __attribute__((ext_vector_type(8)));
typedef float f32x4  __attribute__((ext_vector_type(4)));

struct Args {
  const float* h0_init;
  const float* emb;
  const float* Wih0; const float* Whh0; const float* bih0; const float* bhh0;
  const float* Wih1; const float* Whh1; const float* bih1; const float* bhh1;
  const float* Wout; const float* bout;
  const int*   maxn;
  float* out;
  float* hbuf;                 // [2*BH] h0,h1
  unsigned long long* packed;  // final fp32-key argmax per b (128B stride)
  unsigned* bar;               // monotonic epoch barrier
  const unsigned* wpack;       // bf16 B-fragment packed Wout
  const float* wnormE;         // EPS * ||bf16(w_n)||_2
};

// ---- bf16 helpers ----
__device__ __forceinline__ unsigned short bf16_rne(float f){
  unsigned u = __float_as_uint(f);
  unsigned r = u + 0x7FFFu + ((u >> 16) & 1u);
  return (unsigned short)(r >> 16);
}
__device__ __forceinline__ float bf16v(float f){
  unsigned u = ((unsigned)bf16_rne(f)) << 16;
  return __uint_as_float(u);
}
__device__ __forceinline__ unsigned key32(float f){
  unsigned u = __float_as_uint(f);
  return (u & 0x80000000u) ? ~u : (u | 0x80000000u);
}

// ---- coherent (L3-point) accessors ----
__device__ __forceinline__ unsigned long long cload8(const void* p){
  return __hip_atomic_load((const unsigned long long*)p,
                           __ATOMIC_RELAXED, __HIP_MEMORY_SCOPE_AGENT);
}
__device__ __forceinline__ void cstore4(float* p, float v){
  __hip_atomic_store(p, v, __ATOMIC_RELAXED, __HIP_MEMORY_SCOPE_AGENT);
}
__device__ __forceinline__ void cstore8(void* p, unsigned long long v){
  __hip_atomic_store((unsigned long long*)p, v,
                     __ATOMIC_RELAXED, __HIP_MEMORY_SCOPE_AGENT);
}

// ---- epoch tree barrier: monotonic counters, store-release, no resets ----
// bar layout (u32, 128B stride): [g*32] 8 group counters, [8*32] root, [(9+g)*32] gens
__device__ __forceinline__ void gridbar(unsigned* bar, int bid, unsigned ep){
  __syncthreads();
  if (threadIdx.x == 0){
    asm volatile("s_waitcnt vmcnt(0)" ::: "memory");
    const int g = bid & 7;
    unsigned* gcnt = bar + g*32;
    unsigned* root = bar + 8*32;
    unsigned* gen  = bar + (9+g)*32;
    unsigned go = __hip_atomic_fetch_add(gcnt, 1u, __ATOMIC_RELAXED, __HIP_MEMORY_SCOPE_AGENT);
    if ((go & 31u) == 31u){
      unsigned ro = __hip_atomic_fetch_add(root, 1u, __ATOMIC_RELAXED, __HIP_MEMORY_SCOPE_AGENT);
      if ((ro & 7u) == 7u){
        asm volatile("s_waitcnt vmcnt(0)" ::: "memory");
        #pragma unroll
        for (int i = 0; i < 8; ++i)
          __hip_atomic_store(bar + (9+i)*32, ep, __ATOMIC_RELAXED, __HIP_MEMORY_SCOPE_AGENT);
      }
    }
    while ((int)(__hip_atomic_load(gen, __ATOMIC_RELAXED, __HIP_MEMORY_SCOPE_AGENT) - ep) < 0){
      __builtin_amdgcn_s_sleep(2);
    }
  }
  __syncthreads();
}

// stage 32x512 floats global -> LDS (row stride LDP), coherent 8B loads
__device__ __forceinline__ void stage_h(const float* g, float* s, int tid){
  const unsigned long long* gd = (const unsigned long long*)g;
  #pragma unroll
  for (int n = 0; n < 16; ++n){
    int idx = n*512 + tid;
    int row = idx >> 8;
    int col = idx & 255;
    unsigned long long v = __hip_atomic_load(gd + idx, __ATOMIC_RELAXED,
                                             __HIP_MEMORY_SCOPE_AGENT);
    *(unsigned long long*)(s + row*LDP + col*2) = v;
  }
}

__device__ __forceinline__ float red8(float v){
  v += __shfl_xor(v, 1); v += __shfl_xor(v, 2); v += __shfl_xor(v, 4);
  return v;
}
__device__ __forceinline__ float dot4acc(float4 w, float4 x, float acc){
  return fmaf(w.x,x.x, fmaf(w.y,x.y, fmaf(w.z,x.z, fmaf(w.w,x.w, acc))));
}

// one oct (8 lanes) computes one (b,j) GRU output.
// k-slices rotated by b: bank-quad becomes (2b+lane8)%8 -> 2-way (free) LDS access.
__device__ __forceinline__ void gru_oct(
    const float* xrow, const float* hrow,
    const float* Wih, const float* Whh,
    const float* bih, const float* bhh,
    int j, int b, int lane8, float* hout_g)
{
  const float* wir = Wih + (size_t)j * Hsz;
  const float* whr = Whh + (size_t)j * Hsz;
  const int rot = ((lane8 + b) & 7) << 2;
  float ar=0.f, az=0.f, an=0.f, hr=0.f, hz=0.f, hn=0.f;
  #pragma unroll 4
  for (int i = 0; i < 16; ++i){
    int k = i*32 + rot;
    float4 xv = *(const float4*)(xrow + k);
    float4 hv = *(const float4*)(hrow + k);
    ar = dot4acc(*(const float4*)(wir + k),            xv, ar);
    az = dot4acc(*(const float4*)(wir + 512*512 + k),  xv, az);
    an = dot4acc(*(const float4*)(wir + 2*512*512 + k),xv, an);
    hr = dot4acc(*(const float4*)(whr + k),            hv, hr);
    hz = dot4acc(*(const float4*)(whr + 512*512 + k),  hv, hz);
    hn = dot4acc(*(const float4*)(whr + 2*512*512 + k),hv, hn);
  }
  ar = red8(ar); az = red8(az); an = red8(an);
  hr = red8(hr); hz = red8(hz); hn = red8(hn);
  if (lane8 == 0){
    float r = 1.f/(1.f + expf(-(ar + bih[j]       + hr + bhh[j])));
    float z = 1.f/(1.f + expf(-(az + bih[Hsz+j]   + hz + bhh[Hsz+j])));
    float n = tanhf(an + bih[2*Hsz+j] + r*(hn + bhh[2*Hsz+j]));
    cstore4(hout_g, (1.f - z)*n + z*hrow[j]);
  }
}

// ================= repack: Wout fp32 -> bf16 B-fragments + row norms =================
__global__ __launch_bounds__(512) void repack_kernel(const float* __restrict__ Wout,
                                                     unsigned* __restrict__ wpack,
                                                     float* __restrict__ wnormE){
  const int rb = blockIdx.x;            // 0..249
  const int g = threadIdx.x >> 6;
  const int lane = threadIdx.x & 63;
  const int n = rb*128 + g*16 + (lane & 15);
  const int kq = (lane >> 4) * 8;
  float sumsq = 0.f;
  for (int c = 0; c < 16; ++c){
    const float* p = Wout + (size_t)n*512 + c*32 + kq;
    float4 f0 = *(const float4*)p;
    float4 f1 = *(const float4*)(p + 4);
    unsigned short s0 = bf16_rne(f0.x), s1 = bf16_rne(f0.y),
                   s2 = bf16_rne(f0.z), s3 = bf16_rne(f0.w),
                   s4 = bf16_rne(f1.x), s5 = bf16_rne(f1.y),
                   s6 = bf16_rne(f1.z), s7 = bf16_rne(f1.w);
    float v;
    v = __uint_as_float(((unsigned)s0)<<16); sumsq += v*v;
    v = __uint_as_float(((unsigned)s1)<<16); sumsq += v*v;
    v = __uint_as_float(((unsigned)s2)<<16); sumsq += v*v;
    v = __uint_as_float(((unsigned)s3)<<16); sumsq += v*v;
    v = __uint_as_float(((unsigned)s4)<<16); sumsq += v*v;
    v = __uint_as_float(((unsigned)s5)<<16); sumsq += v*v;
    v = __uint_as_float(((unsigned)s6)<<16); sumsq += v*v;
    v = __uint_as_float(((unsigned)s7)<<16); sumsq += v*v;
    uint4 u;
    u.x = (unsigned)s0 | ((unsigned)s1<<16);
    u.y = (unsigned)s2 | ((unsigned)s3<<16);
    u.z = (unsigned)s4 | ((unsigned)s5<<16);
    u.w = (unsigned)s6 | ((unsigned)s7<<16);
    *(uint4*)(wpack + (size_t)(((rb*8+g)*16 + c))*256 + lane*4) = u;
  }
  sumsq += __shfl_xor(sumsq, 16);
  sumsq += __shfl_xor(sumsq, 32);
  if (lane < 16) wnormE[n] = EPS * sqrtf(sumsq);
}

// ================= main cooperative kernel =================
__global__ __launch_bounds__(NTHR, 1) void decoder_kernel(Args a){
  const int tid = threadIdx.x;
  const int bid = blockIdx.x;
  const int wave = tid >> 6;
  const int lane = tid & 63;
  const int T = a.maxn[0];
  float* h0g = a.hbuf;
  float* h1g = a.hbuf + BH;

  __shared__ float shA[Bsz*LDP];                 // h0 mirror (64.5 KB)
  __shared__ float shB[Bsz*LDP];                 // h1 mirror (fp32, rescore + persist)
  __shared__ unsigned af[16*64*4];               // A-frags (16 KB); aliased as candList
  __shared__ unsigned lbmaxL[32];
  __shared__ float hnormL[32];
  __shared__ int sh_tok[Bsz];
  __shared__ int candCnt;
  int* candList = (int*)af;                      // af is dead after MFMA loop

  unsigned ep = 1;

  for (int t = 0; t < T; ++t){
    // ---- Phase A: GRU layer 0 (h0prev persists in shA from B(t-1)) ----
    if (t == 0) stage_h(a.h0_init, shA, tid);
    if (tid < Bsz){
      int tok;
      if (t == 0) tok = 1;   // SOS
      else        tok = (int)(~(unsigned)(cload8(&a.packed[tid*16]) & 0xffffffffULL));
      sh_tok[tid] = tok;
    }
    __syncthreads();
    {
      int oct = tid >> 3, lane8 = tid & 7;
      int b = oct & 31, jj = oct >> 5;
      int j = bid*2 + jj;
      const float* xrow = a.emb + (size_t)sh_tok[b] * Hsz;
      gru_oct(xrow, shA + b*LDP, a.Wih0, a.Whh0, a.bih0, a.bhh0,
              j, b, lane8, h0g + b*Hsz + j);
    }
    gridbar(a.bar, bid, ep); ++ep;

    // ---- Phase B: harvest token t-1 + zero packed; GRU layer 1 ----
    if (bid == 0 && tid < Bsz){
      if (t > 0){
        unsigned long long p = cload8(&a.packed[tid*16]);
        int tok = (int)(~(unsigned)(p & 0xffffffffULL));
        a.out[tid*T + (t-1)] = (float)tok;
      }
      cstore8(&a.packed[tid*16], 0ULL);
    }
    stage_h(h0g, shA, tid);                        // h0new -> shA (persists to A(t+1))
    if (t == 0) stage_h(a.h0_init + BH, shB, tid); // h1prev only at t=0
    __syncthreads();
    {
      int oct = tid >> 3, lane8 = tid & 7;
      int b = oct & 31, jj = oct >> 5;
      int j = bid*2 + jj;
      gru_oct(shA + b*LDP, shB + b*LDP, a.Wih1, a.Whh1, a.bih1, a.bhh1,
              j, b, lane8, h1g + b*Hsz + j);
    }
    gridbar(a.bar, bid, ep); ++ep;

    // ---- Phase C (fused): stage h1new->shB (all blocks, persists as h1prev);
    //      bf16 MFMA logits + local pruning + exact fp32 rescore + argmax ----
    stage_h(h1g, shB, tid);
    if (tid < 32) lbmaxL[tid] = 0u;
    if (tid == 0) candCnt = 0;
    __syncthreads();
    if (bid < CBLK){
      // norms of bf16-rounded h rows (b-rotated quads: reduced bank conflicts)
      if (tid < 256){
        int b = tid >> 3, lane8 = tid & 7;
        float s = 0.f;
        const float* p0 = shB + b*LDP;
        #pragma unroll
        for (int i = 0; i < 8; ++i){
          int off = i*64 + (((lane8 + b) & 7) << 3);
          float4 v0 = *(const float4*)(p0 + off);
          float4 v1 = *(const float4*)(p0 + off + 4);
          float q;
          q = bf16v(v0.x); s = fmaf(q,q,s);  q = bf16v(v0.y); s = fmaf(q,q,s);
          q = bf16v(v0.z); s = fmaf(q,q,s);  q = bf16v(v0.w); s = fmaf(q,q,s);
          q = bf16v(v1.x); s = fmaf(q,q,s);  q = bf16v(v1.y); s = fmaf(q,q,s);
          q = bf16v(v1.z); s = fmaf(q,q,s);  q = bf16v(v1.w); s = fmaf(q,q,s);
        }
        s = red8(s);
        if (lane8 == 0) hnormL[b] = sqrtf(s);
      }
      // preload this wave's 16 B-fragments
      const unsigned* wbase = a.wpack + (size_t)((bid*8 + wave)*16)*256 + lane*4;
      short8 bw[16];
      #pragma unroll
      for (int c = 0; c < 16; ++c)
        bw[c] = *(const short8*)(wbase + c*256);

      f32x4 accs[2];
      #pragma unroll
      for (int mt = 0; mt < 2; ++mt){
        #pragma unroll
        for (int it = 0; it < 8; ++it){
          int d = it*512 + tid;
          int c = d >> 8, al = (d >> 2) & 63, dw = d & 3;
          int m = mt*16 + (al & 15);
          int k = c*32 + ((al >> 4) * 8) + dw*2;
          float2 fv = *(const float2*)(shB + m*LDP + k);
          unsigned lo = bf16_rne(fv.x);
          unsigned hi = bf16_rne(fv.y);
          af[d] = lo | (hi << 16);
        }
        __syncthreads();
        f32x4 acc = {0.f, 0.f, 0.f, 0.f};
        #pragma unroll
        for (int c = 0; c < 16; ++c){
          short8 av = *(short8*)&af[(c*64 + lane)*4];
          acc = __builtin_amdgcn_mfma_f32_16x16x32_bf16(av, bw[c], acc, 0, 0, 0);
        }
        accs[mt] = acc;
        __syncthreads();
      }
      // epilogue: bounds, block-local prune, exact rescore
      const int n_loc = wave*16 + (lane & 15);
      const int n = bid*128 + n_loc;
      const float bias = a.bout[n];
      const float wn = a.wnormE[n];
      const int quad = lane >> 4;
      float lb8[8], ub8[8];
      #pragma unroll
      for (int mt = 0; mt < 2; ++mt)
        #pragma unroll
        for (int r = 0; r < 4; ++r){
          int m = mt*16 + quad*4 + r;
          float lg = accs[mt][r] + bias;
          float mg = wn * hnormL[m];
          lb8[mt*4+r] = lg - mg;
          ub8[mt*4+r] = lg + mg;
        }
      // per-m max of lb over this wave's 16 n-columns, then LDS atomicMax
      #pragma unroll
      for (int e = 0; e < 8; ++e){
        float v = lb8[e];
        v = fmaxf(v, __shfl_xor(v, 1));
        v = fmaxf(v, __shfl_xor(v, 2));
        v = fmaxf(v, __shfl_xor(v, 4));
        v = fmaxf(v, __shfl_xor(v, 8));
        if ((lane & 15) == 0){
          int m = (e >> 2)*16 + quad*4 + (e & 3);
          atomicMax(&lbmaxL[m], key32(v));
        }
      }
      __syncthreads();
      // candidate scan (af is dead -> candList alias; max 8/lane * 512 = 4096 = cap)
      #pragma unroll
      for (int e = 0; e < 8; ++e){
        int m = (e >> 2)*16 + quad*4 + (e & 3);
        if (key32(ub8[e]) >= lbmaxL[m]){
          int pos = atomicAdd(&candCnt, 1);
          candList[pos] = n_loc*32 + m;
        }
      }
      __syncthreads();
      int nc = candCnt;
      for (int ci = wave; ci < nc; ci += 8){
        int cidx = candList[ci];
        int cn_loc = cidx >> 5, b = cidx & 31;
        int cn = bid*128 + cn_loc;
        const float* wrow = a.Wout + (size_t)cn*512 + lane*8;
        const float* hrow = shB + b*LDP + lane*8;
        float4 w0 = *(const float4*)wrow,  w1 = *(const float4*)(wrow + 4);
        float4 x0 = *(const float4*)hrow,  x1 = *(const float4*)(hrow + 4);
        float d = dot4acc(w0, x0, 0.f);
        d = dot4acc(w1, x1, d);
        d += __shfl_xor(d, 1);  d += __shfl_xor(d, 2);  d += __shfl_xor(d, 4);
        d += __shfl_xor(d, 8);  d += __shfl_xor(d, 16); d += __shfl_xor(d, 32);
        if (lane == 0){
          float lg = d + a.bout[cn];
          unsigned long long key =
              (((unsigned long long)key32(lg)) << 32) | (unsigned)(~(unsigned)cn);
          atomicMax(&a.packed[b*16], key);
        }
      }
    }
    gridbar(a.bar, bid, ep); ++ep;
  }

  // ---- final harvest + final hidden states ----
  if (bid == 0 && tid < Bsz){
    unsigned long long p = cload8(&a.packed[tid*16]);
    int tok = (int)(~(unsigned)(p & 0xffffffffULL));
    a.out[tid*T + (T-1)] = (float)tok;
  }
  int e = bid*NTHR + tid;
  if (e < BH/2){
    unsigned long long v0 = cload8((const unsigned long long*)h0g + e);
    unsigned long long v1 = cload8((const unsigned long long*)h1g + e);
    *((unsigned long long*)(a.out + Bsz*T) + e)      = v0;
    *((unsigned long long*)(a.out + Bsz*T + BH) + e) = v1;
  }
}

// ================= fallback (fp32 logits path) if ws too small =================
__global__ __launch_bounds__(NTHR, 1) void decoder_kernel_fb(Args a){
  const int tid = threadIdx.x;
  const int bid = blockIdx.x;
  const int T = a.maxn[0];
  float* h0g = a.hbuf;
  float* h1g = a.hbuf + BH;
  __shared__ float shA[Bsz*LDP];
  __shared__ float shB[Bsz*LDP];
  __shared__ unsigned long long lbest[32*32];
  __shared__ int sh_tok[Bsz];
  unsigned ep = 1;

  for (int t = 0; t < T; ++t){
    if (t == 0) stage_h(a.h0_init, shA, tid);
    if (tid < Bsz){
      int tok;
      if (t == 0) tok = 1;
      else        tok = (int)(~(unsigned)(cload8(&a.packed[tid*16]) & 0xffffffffULL));
      sh_tok[tid] = tok;
    }
    __syncthreads();
    {
      int oct = tid >> 3, lane8 = tid & 7;
      int b = oct & 31, jj = oct >> 5;
      int j = bid*2 + jj;
      const float* xrow = a.emb + (size_t)sh_tok[b] * Hsz;
      gru_oct(xrow, shA + b*LDP, a.Wih0, a.Whh0, a.bih0, a.bhh0,
              j, b, lane8, h0g + b*Hsz + j);
    }
    gridbar(a.bar, bid, ep); ++ep;
    if (bid == 0 && tid < Bsz){
      if (t > 0){
        unsigned long long p = cload8(&a.packed[tid*16]);
        a.out[tid*T + (t-1)] = (float)((int)(~(unsigned)(p & 0xffffffffULL)));
      }
      cstore8(&a.packed[tid*16], 0ULL);
    }
    stage_h(h0g, shA, tid);
    if (t == 0) stage_h(a.h0_init + BH, shB, tid);
    __syncthreads();
    {
      int oct = tid >> 3, lane8 = tid & 7;
      int b = oct & 31, jj = oct >> 5;
      int j = bid*2 + jj;
      gru_oct(shA + b*LDP, shB + b*LDP, a.Wih1, a.Whh1, a.bih1, a.bhh1,
              j, b, lane8, h1g + b*Hsz + j);
    }
    gridbar(a.bar, bid, ep); ++ep;
    stage_h(h1g, shB, tid);
    __syncthreads();
    if (bid < CBLK){
      const int quad = tid >> 2, l4 = tid & 3;
      const int rg = quad & 31, bg = quad >> 5;
      const int rowbase = bid*128 + rg*4;
      const float* wr = a.Wout + (size_t)rowbase * Hsz;
      const float* hb = shB + bg*8*LDP;
      float acc[4][8];
      #pragma unroll
      for (int s = 0; s < 4; ++s)
        #pragma unroll
        for (int j = 0; j < 8; ++j) acc[s][j] = 0.f;
      #pragma unroll 2
      for (int i = 0; i < 32; ++i){
        const int k = i*16 + l4*4;
        float4 wv[4], hv[8];
        #pragma unroll
        for (int s = 0; s < 4; ++s) wv[s] = *(const float4*)(wr + (size_t)s*Hsz + k);
        #pragma unroll
        for (int j = 0; j < 8; ++j) hv[j] = *(const float4*)(hb + j*LDP + k);
        #pragma unroll
        for (int s = 0; s < 4; ++s)
          #pragma unroll
          for (int j = 0; j < 8; ++j) acc[s][j] = dot4acc(wv[s], hv[j], acc[s][j]);
      }
      #pragma unroll
      for (int s = 0; s < 4; ++s)
        #pragma unroll
        for (int j = 0; j < 8; ++j){
          float v = acc[s][j];
          v += __shfl_xor(v, 1); v += __shfl_xor(v, 2);
          acc[s][j] = v;
        }
      if (l4 == 0){
        float4 bv = *(const float4*)(a.bout + rowbase);
        float bb[4] = {bv.x, bv.y, bv.z, bv.w};
        #pragma unroll
        for (int j = 0; j < 8; ++j){
          float best = -3.4e38f; int bi = rowbase;
          #pragma unroll
          for (int s = 0; s < 4; ++s){
            float lv = acc[s][j] + bb[s];
            if (lv > best){ best = lv; bi = rowbase + s; }
          }
          unsigned u = __float_as_uint(best);
          unsigned key = (u & 0x80000000u) ? ~u : (u | 0x80000000u);
          lbest[rg*32 + bg*8 + j] =
              ((unsigned long long)key << 32) | (unsigned)(~(unsigned)bi);
        }
      }
      __syncthreads();
      if (tid < Bsz){
        unsigned long long m = lbest[tid];
        #pragma unroll 4
        for (int r = 1; r < 32; ++r){
          unsigned long long c = lbest[r*32 + tid];
          m = (c > m) ? c : m;
        }
        atomicMax(&a.packed[tid*16], m);
      }
    }
    gridbar(a.bar, bid, ep); ++ep;
  }
  if (bid == 0 && tid < Bsz){
    unsigned long long p = cload8(&a.packed[tid*16]);
    a.out[tid*T + (T-1)] = (float)((int)(~(unsigned)(p & 0xffffffffULL)));
  }
  int e = bid*NTHR + tid;
  if (e < BH/2){
    unsigned long long v0 = cload8((const unsigned long long*)h0g + e);
    unsigned long long v1 = cload8((const unsigned long long*)h1g + e);
    *((unsigned long long*)(a.out + Bsz*T) + e)      = v0;
    *((unsigned long long*)(a.out + Bsz*T + BH) + e) = v1;
  }
}

extern "C" void kernel_launch(void* const* d_in, const int* in_sizes, int n_in,
                              void* d_out, int out_size, void* d_ws, size_t ws_size,
                              hipStream_t stream){
  Args a;
  a.h0_init = (const float*)d_in[0];
  a.emb  = (const float*)d_in[1];
  a.Wih0 = (const float*)d_in[2];
  a.Whh0 = (const float*)d_in[3];
  a.bih0 = (const float*)d_in[4];
  a.bhh0 = (const float*)d_in[5];
  a.Wih1 = (const float*)d_in[6];
  a.Whh1 = (const float*)d_in[7];
  a.bih1 = (const float*)d_in[8];
  a.bhh1 = (const float*)d_in[9];
  a.Wout = (const float*)d_in[10];
  a.bout = (const float*)d_in[11];
  a.maxn = (const int*)d_in[12];
  a.out  = (float*)d_out;
  char* wsb = (char*)d_ws;
  a.hbuf   = (float*)(wsb + WS_HBUF);
  a.packed = (unsigned long long*)(wsb + WS_PACKED);
  a.bar    = (unsigned*)(wsb + WS_BAR);
  a.wpack  = (const unsigned*)(wsb + WS_WPACK);
  a.wnormE = (const float*)(wsb + WS_WNORM);

  // zero packed + (plb region) + bar; ws re-poisoned 0xAA before every call
  hipMemsetAsync(wsb + WS_PACKED, 0, 12288, stream);

  void* params[] = { &a };
  if (ws_size >= (size_t)WS_NEEDED){
    repack_kernel<<<CBLK, 512, 0, stream>>>(a.Wout, (unsigned*)a.wpack, (float*)a.wnormE);
    hipLaunchCooperativeKernel((void*)decoder_kernel, dim3(NBLK), dim3(NTHR),
                               params, 0, stream);
  } else {
    hipLaunchCooperativeKernel((void*)decoder_kernel_fb, dim3(NBLK), dim3(NTHR),
                               params, 0, stream);
  }
}